// Round 10
// baseline (48.031 us; speedup 1.0000x reference)
//
#include <hip/hip_runtime.h>
#include <math.h>

#define BATCH 128
#define NPWM 512
#define LEN 1000
#define NEXT 1024     // 2*NPWM (fwd + revcomp interleaved: f_ext = 2*f + strand)
#define KSLOT 80      // kk padded 19->20, slot = kk*4 + c

typedef __bf16 bf16x4 __attribute__((ext_vector_type(4)));
typedef __bf16 bf16x8 __attribute__((ext_vector_type(8)));
typedef float  f32x16 __attribute__((ext_vector_type(16)));

#define MFMA32(a, b, c) __builtin_amdgcn_mfma_f32_32x32x16_bf16(a, b, c, 0, 0, 0)

// ---- prepack W: (512,4,19) fp32 -> (1024,80) bf16 hi/lo, zeros at pad slots ----
__global__ __launch_bounds__(256)
void prepack_w(const float* __restrict__ w, __bf16* __restrict__ whi, __bf16* __restrict__ wlo)
{
    int idx = blockIdx.x * 256 + threadIdx.x;
    if (idx >= NEXT * KSLOT) return;
    int fe = idx / KSLOT;
    int t  = idx - fe * KSLOT;
    int kk = t >> 2;
    int c  = t & 3;
    int f      = fe >> 1;
    int strand = fe & 1;
    float v = 0.0f;
    if (kk < 19)
        v = strand ? w[f*76 + (3-c)*19 + (18-kk)]   // reverse-complement
                   : w[f*76 + c*19 + kk];
    __bf16 h = (__bf16)v;
    whi[idx] = h;
    wlo[idx] = (__bf16)(v - (float)h);
}

// 16B B-fragment as two conflict-free ds_read_b64
#define LD(EO) __extension__ ({                                          \
    bf16x4 p0_ = *(const bf16x4*)(H + (EO));                             \
    bf16x4 p1_ = *(const bf16x4*)(H + (EO) + 4);                         \
    __builtin_shufflevector(p0_, p1_, 0,1,2,3,4,5,6,7); })

// load 5 B fragments for iter IT and issue the 10-MFMA chain into ACC
#define CHAIN(ACC, IT)                                                   \
  {                                                                      \
    const int e0_ = (IT)*128 + cgh4;                                     \
    bf16x8 g0 = LD(e0_),      g1 = LD(e0_ + 16), g2 = LD(e0_ + 32),      \
           g3 = LD(e0_ + 48), g4 = LD(e0_ + 64);                         \
    ACC = (f32x16){};                                                    \
    ACC = MFMA32(wah[0], g0, ACC); ACC = MFMA32(wal[0], g0, ACC);        \
    ACC = MFMA32(wah[1], g1, ACC); ACC = MFMA32(wal[1], g1, ACC);        \
    ACC = MFMA32(wah[2], g2, ACC); ACC = MFMA32(wal[2], g2, ACC);        \
    ACC = MFMA32(wah[3], g3, ACC); ACC = MFMA32(wal[3], g3, ACC);        \
    ACC = MFMA32(wah[4], g4, ACC); ACC = MFMA32(wal[4], g4, ACC);        \
  }

#define MERGE(ACC)                                                       \
  { _Pragma("unroll") for (int r = 0; r < 16; ++r)                       \
      m[r] = fmaxf(m[r], ACC[r]); }

#define MERGEM(ACC) { if (col < 22) MERGE(ACC) }   // iter 30: pos = 960+col < 982

// ---- main: 2-term w-split GEMM, 32x32x16, acc double-pipeline, fused max ----
// block = 4 waves = 2 filter-tiles x 2 position-halves; grid = (128,16).
// Key schedule property: every MERGE(X) is preceded in program order by a full
// independent CHAIN into the other accumulator -> no issue-stall at the merge.
__global__ __launch_bounds__(256, 4)
void pwm_mfma(const float* __restrict__ x,
              const __bf16* __restrict__ whi,
              const __bf16* __restrict__ wlo,
              float* __restrict__ out)
{
    __shared__ __align__(16) __bf16 H[4096];   // bf16(x), [pos][c], pos 0..1023 (tail 0)
    __shared__ float red[2][64];

    const int tid   = threadIdx.x;
    const int b     = blockIdx.x;
    const int by    = blockIdx.y;   // 0..15: which 64 f_ext
    const int lane  = tid & 63;
    const int wave  = tid >> 6;
    const int fhalf = wave & 1;     // which 32-filter tile
    const int wp    = wave >> 1;    // position half
    const int col   = lane & 31;
    const int gh    = lane >> 5;

    // stage bf16(x[b]) position-major [pos][c]; 8B LDS writes, tail zeroed
    for (int i = tid; i < 1024; i += 256) {
        bf16x4 hv;
        #pragma unroll
        for (int c = 0; c < 4; ++c) {
            float v = (i < LEN) ? x[(size_t)b*4000 + c*1000 + i] : 0.0f;
            hv[c] = (__bf16)v;
        }
        *(bf16x4*)(H + i*4) = hv;
    }

    // A fragments (W hi/lo) -> regs: lane holds W[f0+col][k = t*16 + gh*8 + j]
    bf16x8 wah[5], wal[5];
    {
        const int f0 = by*64 + fhalf*32;
        #pragma unroll
        for (int t = 0; t < 5; ++t) {
            const size_t o = (size_t)(f0 + col)*KSLOT + t*16 + gh*8;
            wah[t] = *(const bf16x8*)(whi + o);
            wal[t] = *(const bf16x8*)(wlo + o);
        }
    }
    __syncthreads();

    // B element base: slot k = t*16 + gh*8 + j -> x element (pos + t*4 + 2gh)*4 + c
    const int cgh4 = (col + 2*gh)*4;

    f32x16 m;
    #pragma unroll
    for (int r = 0; r < 16; ++r) m[r] = -INFINITY;

    f32x16 aA, aB;
    if (wp == 0) {                       // iters 0..15
        CHAIN(aA, 0)
        for (int bb = 0; bb < 7; ++bb) {
            CHAIN(aB, 1 + 2*bb) MERGE(aA)
            CHAIN(aA, 2 + 2*bb) MERGE(aB)
        }
        CHAIN(aB, 15) MERGE(aA) MERGE(aB)
    } else {                             // iters 16..30 (30 masked)
        CHAIN(aA, 16)
        for (int bb = 0; bb < 6; ++bb) {
            CHAIN(aB, 17 + 2*bb) MERGE(aA)
            CHAIN(aA, 18 + 2*bb) MERGE(aB)
        }
        CHAIN(aB, 29) MERGE(aA)
        CHAIN(aA, 30) MERGE(aB) MERGEM(aA)
    }

    // reduce over the 32 position-columns (within each 32-lane half)
    #pragma unroll
    for (int off = 1; off <= 16; off <<= 1)
        #pragma unroll
        for (int r = 0; r < 16; ++r)
            m[r] = fmaxf(m[r], __shfl_xor(m[r], off, 64));

    // D row (f_ext within 32-tile) = (r&3) + 8*(r>>2) + 4*gh
    if (col == 0) {
        #pragma unroll
        for (int r = 0; r < 16; ++r) {
            const int row = (r & 3) + 8*(r >> 2) + 4*gh;
            red[wp][fhalf*32 + row] = m[r];
        }
    }
    __syncthreads();
    if (tid < 32) {   // combine strand pairs (f_ext = 2f, 2f+1) and position halves
        float v0 = fmaxf(red[0][2*tid], red[0][2*tid+1]);
        float v1 = fmaxf(red[1][2*tid], red[1][2*tid+1]);
        out[(size_t)b*NPWM + by*32 + tid] = fmaxf(v0, v1);
    }
}

extern "C" void kernel_launch(void* const* d_in, const int* in_sizes, int n_in,
                              void* d_out, int out_size, void* d_ws, size_t ws_size,
                              hipStream_t stream)
{
    const float* x = (const float*)d_in[0];   // (128, 4, 1000)
    const float* w = (const float*)d_in[1];   // (512, 4, 19)
    float* out = (float*)d_out;               // (128, 512)

    __bf16* whi = (__bf16*)d_ws;              // 1024*80 bf16
    __bf16* wlo = whi + NEXT*KSLOT;

    prepack_w<<<dim3((NEXT*KSLOT + 255)/256), 256, 0, stream>>>(w, whi, wlo);
    pwm_mfma<<<dim3(BATCH, 16), 256, 0, stream>>>(x, whi, wlo, out);
}

// Round 11
// 46.733 us; speedup vs baseline: 1.0278x; 1.0278x over previous
//
#include <hip/hip_runtime.h>
#include <math.h>

#define BATCH 128
#define NPWM 512
#define LEN 1000
#define NEXT 1024     // 2*NPWM (fwd + revcomp interleaved: f_ext = 2*f + strand)
#define KSLOT 80      // kk padded 19->20, slot = kk*4 + c

typedef __bf16 bf16x4 __attribute__((ext_vector_type(4)));
typedef __bf16 bf16x8 __attribute__((ext_vector_type(8)));
typedef float  f32x16 __attribute__((ext_vector_type(16)));

#define MFMA32(a, b, c) __builtin_amdgcn_mfma_f32_32x32x16_bf16(a, b, c, 0, 0, 0)

// ---- prepack W: (512,4,19) fp32 -> (1024,80) bf16 hi/lo, zeros at pad slots ----
__global__ __launch_bounds__(256)
void prepack_w(const float* __restrict__ w, __bf16* __restrict__ whi, __bf16* __restrict__ wlo)
{
    int idx = blockIdx.x * 256 + threadIdx.x;
    if (idx >= NEXT * KSLOT) return;
    int fe = idx / KSLOT;
    int t  = idx - fe * KSLOT;
    int kk = t >> 2;
    int c  = t & 3;
    int f      = fe >> 1;
    int strand = fe & 1;
    float v = 0.0f;
    if (kk < 19)
        v = strand ? w[f*76 + (3-c)*19 + (18-kk)]   // reverse-complement
                   : w[f*76 + c*19 + kk];
    __bf16 h = (__bf16)v;
    whi[idx] = h;
    wlo[idx] = (__bf16)(v - (float)h);
}

// 16B B-fragment as two conflict-free ds_read_b64
#define LD(HB, EO) __extension__ ({                                      \
    bf16x4 p0_ = *(const bf16x4*)((HB) + (EO));                          \
    bf16x4 p1_ = *(const bf16x4*)((HB) + (EO) + 4);                      \
    __builtin_shufflevector(p0_, p1_, 0,1,2,3,4,5,6,7); })

// one 32-position tile: 5 B-frag loads + 10-MFMA chain (C-in = hoisted zero) + merge
#define KITER(HB, IT, MASKED)                                            \
  {                                                                      \
    const int e0_ = (IT)*128 + cgh4;                                     \
    bf16x8 g0 = LD(HB, e0_),      g1 = LD(HB, e0_ + 16),                 \
           g2 = LD(HB, e0_ + 32), g3 = LD(HB, e0_ + 48),                 \
           g4 = LD(HB, e0_ + 64);                                        \
    f32x16 a;                                                            \
    a = MFMA32(wah[0], g0, zc); a = MFMA32(wal[0], g0, a);               \
    a = MFMA32(wah[1], g1, a);  a = MFMA32(wal[1], g1, a);               \
    a = MFMA32(wah[2], g2, a);  a = MFMA32(wal[2], g2, a);               \
    a = MFMA32(wah[3], g3, a);  a = MFMA32(wal[3], g3, a);               \
    a = MFMA32(wah[4], g4, a);  a = MFMA32(wal[4], g4, a);               \
    if (!(MASKED) || col < 22) {                                         \
      _Pragma("unroll") for (int r = 0; r < 16; ++r)                     \
        m[r] = fmaxf(m[r], a[r]);                                        \
    }                                                                    \
  }

#define KSWEEP(HB)                                                       \
    if (wp == 0) { for (int it = 0; it < 16; ++it) KITER(HB, it, false) }\
    else { for (int it = 16; it < 30; ++it) KITER(HB, it, false)         \
           KITER(HB, 30, true) }

#define REDUCE_STORE(BIDX)                                               \
    _Pragma("unroll")                                                    \
    for (int off = 1; off <= 16; off <<= 1)                              \
      _Pragma("unroll")                                                  \
      for (int r = 0; r < 16; ++r)                                       \
        m[r] = fmaxf(m[r], __shfl_xor(m[r], off, 64));                   \
    if (col == 0) {                                                      \
      _Pragma("unroll")                                                  \
      for (int r = 0; r < 16; ++r) {                                     \
        const int row = (r & 3) + 8*(r >> 2) + 4*gh;                     \
        red[wp][fhalf*32 + row] = m[r];                                  \
      }                                                                  \
    }                                                                    \
    __syncthreads();                                                     \
    if (tid < 32) {                                                      \
      float v0_ = fmaxf(red[0][2*tid], red[0][2*tid+1]);                 \
      float v1_ = fmaxf(red[1][2*tid], red[1][2*tid+1]);                 \
      out[(size_t)(BIDX)*NPWM + by*32 + tid] = fmaxf(v0_, v1_);          \
    }

// ---- main: 2-term w-split GEMM, 32x32x16, 2 batches/block, overlapped staging ----
// block = 4 waves = 2 filter-tiles x 2 position-halves; grid = (64,16) = 4 blocks/CU.
// Batch-1 global loads issue BEFORE batch-0 compute (latency hidden under MFMAs);
// the LDS write of batch 1 targets the idle H[1] buffer after batch-0 compute.
__global__ __launch_bounds__(256, 2)
void pwm_mfma(const float* __restrict__ x,
              const __bf16* __restrict__ whi,
              const __bf16* __restrict__ wlo,
              float* __restrict__ out)
{
    __shared__ __align__(16) __bf16 H[2][4096];  // bf16(x), [bb][pos*4+c], tail 0
    __shared__ float red[2][64];

    const int tid   = threadIdx.x;
    const int b0    = blockIdx.x * 2;
    const int by    = blockIdx.y;   // 0..15: which 64 f_ext
    const int lane  = tid & 63;
    const int wave  = tid >> 6;
    const int fhalf = wave & 1;     // which 32-filter tile
    const int wp    = wave >> 1;    // position half
    const int col   = lane & 31;
    const int gh    = lane >> 5;

    // A fragments (W hi/lo) -> regs: lane holds W[f0+col][k = t*16 + gh*8 + j]
    bf16x8 wah[5], wal[5];
    {
        const int f0 = by*64 + fhalf*32;
        #pragma unroll
        for (int t = 0; t < 5; ++t) {
            const size_t o = (size_t)(f0 + col)*KSLOT + t*16 + gh*8;
            wah[t] = *(const bf16x8*)(whi + o);
            wal[t] = *(const bf16x8*)(wlo + o);
        }
    }

    // batch-0 x -> regs -> LDS; batch-1 x -> regs (write deferred past batch-0 compute)
    float xs0[16], xs1[16];
    #pragma unroll
    for (int j = 0; j < 4; ++j) {
        const int p = tid + 256*j;
        #pragma unroll
        for (int c = 0; c < 4; ++c)
            xs0[j*4+c] = (p < LEN) ? x[(size_t)b0*4000 + c*1000 + p] : 0.0f;
    }
    #pragma unroll
    for (int j = 0; j < 4; ++j) {
        const int p = tid + 256*j;
        bf16x4 hv;
        #pragma unroll
        for (int c = 0; c < 4; ++c) hv[c] = (__bf16)xs0[j*4+c];
        *(bf16x4*)(&H[0][p*4]) = hv;   // stride-8B across threads: conflict-free
    }
    #pragma unroll
    for (int j = 0; j < 4; ++j) {
        const int p = tid + 256*j;
        #pragma unroll
        for (int c = 0; c < 4; ++c)
            xs1[j*4+c] = (p < LEN) ? x[(size_t)(b0+1)*4000 + c*1000 + p] : 0.0f;
    }
    __syncthreads();

    const int cgh4 = (col + 2*gh)*4;
    const f32x16 zc = {};   // loop-invariant zero C-in (kills per-iter acc init)

    // ---- batch 0 ----
    f32x16 m;
    #pragma unroll
    for (int r = 0; r < 16; ++r) m[r] = -INFINITY;
    { const __bf16* Hb = &H[0][0]; KSWEEP(Hb) }

    // stage batch 1 into H[1] (loads long since landed; separate buffer, no race)
    #pragma unroll
    for (int j = 0; j < 4; ++j) {
        const int p = tid + 256*j;
        bf16x4 hv;
        #pragma unroll
        for (int c = 0; c < 4; ++c) hv[c] = (__bf16)xs1[j*4+c];
        *(bf16x4*)(&H[1][p*4]) = hv;
    }

    REDUCE_STORE(b0)        // contains the barrier that also publishes H[1]
    __syncthreads();        // protect red[] before reuse

    // ---- batch 1 ----
    #pragma unroll
    for (int r = 0; r < 16; ++r) m[r] = -INFINITY;
    { const __bf16* Hb = &H[1][0]; KSWEEP(Hb) }

    REDUCE_STORE(b0 + 1)
}

extern "C" void kernel_launch(void* const* d_in, const int* in_sizes, int n_in,
                              void* d_out, int out_size, void* d_ws, size_t ws_size,
                              hipStream_t stream)
{
    const float* x = (const float*)d_in[0];   // (128, 4, 1000)
    const float* w = (const float*)d_in[1];   // (512, 4, 19)
    float* out = (float*)d_out;               // (128, 512)

    __bf16* whi = (__bf16*)d_ws;              // 1024*80 bf16
    __bf16* wlo = whi + NEXT*KSLOT;

    prepack_w<<<dim3((NEXT*KSLOT + 255)/256), 256, 0, stream>>>(w, whi, wlo);
    pwm_mfma<<<dim3(BATCH/2, 16), 256, 0, stream>>>(x, whi, wlo, out);
}